// Round 1
// baseline (623.246 us; speedup 1.0000x reference)
//
#include <hip/hip_runtime.h>
#include <cstddef>

#define NB 16
#define NQ 300
#define DM 256
#define NHD 8
#define HDM 32
#define LV_ 8400

// ---------------------------------------------------------------------------
// Kernel 1: v = value @ Wv + bv   (M=134400, N=K=256), fp32 SGEMM
// 128x128 block tile, BK=8, 256 threads, 8x8 microtile as 2x2 blocks of 4x4.
// ---------------------------------------------------------------------------
__global__ __launch_bounds__(256) void vproj_kernel(
    const float* __restrict__ A, const float* __restrict__ W,
    const float* __restrict__ bias, float* __restrict__ C) {
  __shared__ float As[8][128];
  __shared__ float Bs[8][128];
  const int tid = threadIdx.x;
  const int tx = tid & 15;   // column group
  const int ty = tid >> 4;   // row group
  const size_t row0 = (size_t)blockIdx.x * 128;
  const int col0 = blockIdx.y * 128;

  // staging-load assignments
  const int arow = tid >> 1;        // 0..127
  const int akg  = (tid & 1) * 4;   // 0 or 4
  const int bkrow = tid >> 5;       // 0..7
  const int bcol  = (tid & 31) * 4; // 0..124

  const float* Ap = A + (row0 + arow) * DM + akg;
  const float* Wp = W + (size_t)bkrow * DM + col0 + bcol;

  float acc[2][2][4][4];
  #pragma unroll
  for (int ra = 0; ra < 2; ++ra)
    #pragma unroll
    for (int cb = 0; cb < 2; ++cb)
      #pragma unroll
      for (int i = 0; i < 4; ++i)
        #pragma unroll
        for (int j = 0; j < 4; ++j) acc[ra][cb][i][j] = 0.f;

  for (int kk = 0; kk < DM; kk += 8) {
    const float4 va = *(const float4*)(Ap + kk);
    const float4 wv = *(const float4*)(Wp + (size_t)kk * DM);
    __syncthreads();
    As[akg + 0][arow] = va.x;
    As[akg + 1][arow] = va.y;
    As[akg + 2][arow] = va.z;
    As[akg + 3][arow] = va.w;
    *(float4*)&Bs[bkrow][bcol] = wv;
    __syncthreads();
    #pragma unroll
    for (int k = 0; k < 8; ++k) {
      float a[2][4], bfr[2][4];
      *(float4*)a[0]   = *(const float4*)&As[k][ty * 4];
      *(float4*)a[1]   = *(const float4*)&As[k][64 + ty * 4];
      *(float4*)bfr[0] = *(const float4*)&Bs[k][tx * 4];
      *(float4*)bfr[1] = *(const float4*)&Bs[k][64 + tx * 4];
      #pragma unroll
      for (int ra = 0; ra < 2; ++ra)
        #pragma unroll
        for (int cb = 0; cb < 2; ++cb)
          #pragma unroll
          for (int i = 0; i < 4; ++i)
            #pragma unroll
            for (int j = 0; j < 4; ++j)
              acc[ra][cb][i][j] = fmaf(a[ra][i], bfr[cb][j], acc[ra][cb][i][j]);
    }
  }

  float4 bia[2];
  bia[0] = *(const float4*)&bias[col0 + tx * 4];
  bia[1] = *(const float4*)&bias[col0 + 64 + tx * 4];
  #pragma unroll
  for (int ra = 0; ra < 2; ++ra)
    #pragma unroll
    for (int i = 0; i < 4; ++i) {
      const size_t r = row0 + ra * 64 + ty * 4 + i;
      #pragma unroll
      for (int cb = 0; cb < 2; ++cb) {
        const float* bb = (const float*)&bia[cb];
        float4 o;
        o.x = acc[ra][cb][i][0] + bb[0];
        o.y = acc[ra][cb][i][1] + bb[1];
        o.z = acc[ra][cb][i][2] + bb[2];
        o.w = acc[ra][cb][i][3] + bb[3];
        *(float4*)&C[r * DM + col0 + cb * 64 + tx * 4] = o;
      }
    }
}

// ---------------------------------------------------------------------------
// Kernel 2: fused offsets/attn projection + softmax + deformable sampling +
// output projection. One block per (b,q); 256 threads.
// ---------------------------------------------------------------------------
__global__ __launch_bounds__(256) void msda_kernel(
    const float* __restrict__ query, const float* __restrict__ refp,
    const float* __restrict__ v,
    const float* __restrict__ Woff, const float* __restrict__ boff,
    const float* __restrict__ Wattn, const float* __restrict__ battn,
    const float* __restrict__ Wout, const float* __restrict__ bout,
    float* __restrict__ out) {
  const int bq = blockIdx.x;
  const int b = bq / NQ;
  const int t = threadIdx.x;
  __shared__ float q_sh[256];
  __shared__ float off_sh[192];
  __shared__ float aw_sh[96];
  __shared__ float mid_sh[256];
  __shared__ float ref_sh[2];

  q_sh[t] = query[(size_t)bq * DM + t];
  if (t < 2) ref_sh[t] = refp[bq * 4 + t];
  __syncthreads();

  // projections: 192 offset cols + 96 attn-logit cols = 288 outputs
  if (t < 192) {
    float s = boff[t];
    #pragma unroll 4
    for (int k = 0; k < 256; ++k) s = fmaf(q_sh[k], Woff[k * 192 + t], s);
    off_sh[t] = s;
  } else {
    const int col = t - 192;
    float s = battn[col];
    #pragma unroll 4
    for (int k = 0; k < 256; ++k) s = fmaf(q_sh[k], Wattn[k * 96 + col], s);
    aw_sh[col] = s;
  }
  if (t < 32) {
    const int col = 64 + t;
    float s = battn[col];
    #pragma unroll 4
    for (int k = 0; k < 256; ++k) s = fmaf(q_sh[k], Wattn[k * 96 + col], s);
    aw_sh[col] = s;
  }
  __syncthreads();

  // softmax over the 12 (level,point) logits of each head
  if (t < 8) {
    float m = -1e30f;
    #pragma unroll
    for (int i = 0; i < 12; ++i) m = fmaxf(m, aw_sh[t * 12 + i]);
    float e[12], s = 0.f;
    #pragma unroll
    for (int i = 0; i < 12; ++i) { e[i] = __expf(aw_sh[t * 12 + i] - m); s += e[i]; }
    const float inv = 1.f / s;
    #pragma unroll
    for (int i = 0; i < 12; ++i) aw_sh[t * 12 + i] = e[i] * inv;
  }
  __syncthreads();

  // bilinear deformable sampling; lane = (head, dim) so corner reads coalesce
  const int h = t >> 5, d = t & 31;
  const float refx = ref_sh[0], refy = ref_sh[1];
  const float* vb = v + (size_t)b * LV_ * DM + h * HDM + d;
  float acc = 0.f;
  const int LH[3] = {80, 40, 20};
  const int LW[3] = {80, 40, 20};
  const int LS[3] = {0, 6400, 8000};
  #pragma unroll
  for (int l = 0; l < 3; ++l) {
    const int hh = LH[l], ww = LW[l], st = LS[l];
    #pragma unroll
    for (int p = 0; p < 4; ++p) {
      const int oi = ((h * 3 + l) * 4 + p) * 2;
      const float aw = aw_sh[h * 12 + l * 4 + p];
      const float sx = fminf(fmaxf(refx + off_sh[oi], 0.f), 1.f);
      const float sy = fminf(fmaxf(refy + off_sh[oi + 1], 0.f), 1.f);
      // align_corners=False: px = ((2s-1)+1)*w/2 - 0.5 = s*w - 0.5
      const float px = sx * (float)ww - 0.5f;
      const float py = sy * (float)hh - 0.5f;
      const float x0f = floorf(px), y0f = floorf(py);
      const float fx = px - x0f, fy = py - y0f;
      const int x0 = (int)x0f, y0 = (int)y0f;
      const int x1 = x0 + 1, y1 = y0 + 1;
      const bool vx0 = (x0 >= 0) & (x0 < ww), vx1 = (x1 >= 0) & (x1 < ww);
      const bool vy0 = (y0 >= 0) & (y0 < hh), vy1 = (y1 >= 0) & (y1 < hh);
      const float w00 = (1.f - fx) * (1.f - fy) * ((vx0 & vy0) ? 1.f : 0.f);
      const float w10 = fx * (1.f - fy) * ((vx1 & vy0) ? 1.f : 0.f);
      const float w01 = (1.f - fx) * fy * ((vx0 & vy1) ? 1.f : 0.f);
      const float w11 = fx * fy * ((vx1 & vy1) ? 1.f : 0.f);
      const int x0c = min(max(x0, 0), ww - 1), x1c = min(max(x1, 0), ww - 1);
      const int y0c = min(max(y0, 0), hh - 1), y1c = min(max(y1, 0), hh - 1);
      const float v00 = vb[(size_t)(st + y0c * ww + x0c) * DM];
      const float v10 = vb[(size_t)(st + y0c * ww + x1c) * DM];
      const float v01 = vb[(size_t)(st + y1c * ww + x0c) * DM];
      const float v11 = vb[(size_t)(st + y1c * ww + x1c) * DM];
      acc += aw * (w00 * v00 + w10 * v10 + w01 * v01 + w11 * v11);
    }
  }
  mid_sh[t] = acc;  // t == h*32+d == d_model index
  __syncthreads();

  // output projection
  float s = bout[t];
  #pragma unroll 4
  for (int k = 0; k < 256; ++k) s = fmaf(mid_sh[k], Wout[k * DM + t], s);
  out[(size_t)bq * DM + t] = s;
}

extern "C" void kernel_launch(void* const* d_in, const int* in_sizes, int n_in,
                              void* d_out, int out_size, void* d_ws, size_t ws_size,
                              hipStream_t stream) {
  (void)in_sizes; (void)n_in; (void)out_size; (void)ws_size;
  const float* query = (const float*)d_in[0];
  const float* refp  = (const float*)d_in[1];
  const float* value = (const float*)d_in[2];
  const float* Wv    = (const float*)d_in[3];
  const float* bv    = (const float*)d_in[4];
  const float* Woff  = (const float*)d_in[5];
  const float* boff  = (const float*)d_in[6];
  const float* Wattn = (const float*)d_in[7];
  const float* battn = (const float*)d_in[8];
  const float* Wout  = (const float*)d_in[9];
  const float* bout  = (const float*)d_in[10];
  float* out = (float*)d_out;
  float* v   = (float*)d_ws;  // (B, LV, 256) fp32 = 137.6 MB

  dim3 g1((NB * LV_) / 128, 2);
  vproj_kernel<<<g1, 256, 0, stream>>>(value, Wv, bv, v);
  msda_kernel<<<NB * NQ, 256, 0, stream>>>(query, refp, v, Woff, boff,
                                           Wattn, battn, Wout, bout, out);
}

// Round 2
// 352.503 us; speedup vs baseline: 1.7681x; 1.7681x over previous
//
#include <hip/hip_runtime.h>
#include <cstddef>

#define NB 16
#define NQ 300
#define DM 256
#define LV_ 8400

typedef __attribute__((ext_vector_type(8))) short short8;
typedef __attribute__((ext_vector_type(4))) float f32x4;

static __device__ __forceinline__ unsigned short bf16_rne(float f) {
  unsigned int u = __builtin_bit_cast(unsigned int, f);
  u += 0x7FFFu + ((u >> 16) & 1u);
  return (unsigned short)(u >> 16);
}

static __device__ __forceinline__ void split_bf16(float f, short& hi, short& lo) {
  unsigned int u = __builtin_bit_cast(unsigned int, f);
  unsigned int hr = (u + 0x7FFFu + ((u >> 16) & 1u)) & 0xFFFF0000u;
  hi = (short)(hr >> 16);
  float r = f - __builtin_bit_cast(float, hr);
  unsigned int v = __builtin_bit_cast(unsigned int, r);
  lo = (short)((v + 0x7FFFu + ((v >> 16) & 1u)) >> 16);
}

// ---------------------------------------------------------------------------
// Kernel 0: transpose + hi/lo bf16 split of Wv (256x256).  Wt*[n][k].
// ---------------------------------------------------------------------------
__global__ void wconv_kernel(const float* __restrict__ W,
                             short* __restrict__ Wth, short* __restrict__ Wtl) {
  const int n = blockIdx.x, k = threadIdx.x;
  short h, l;
  split_bf16(W[k * DM + n], h, l);
  Wth[n * DM + k] = h;
  Wtl[n * DM + k] = l;
}

// ---------------------------------------------------------------------------
// Kernel 1: v = value @ Wv + bv via split-bf16 MFMA (error ~2^-17).
// M=134400, N=K=256. 128x128 tile, BK=32, 4 waves in 2x2, each wave 4x4
// tiles of 16x16x32.  Output stored bf16.
// ---------------------------------------------------------------------------
__global__ __launch_bounds__(256) void vproj_mfma(
    const float* __restrict__ A, const short* __restrict__ Wth,
    const short* __restrict__ Wtl, const float* __restrict__ bias,
    unsigned short* __restrict__ V) {
  // LDS layout: [kchunk(8k each)][row][8] bf16 so frag reads are one b128
  __shared__ short Ah[4][128][8], Al[4][128][8];
  __shared__ short Bh[4][128][8], Bl[4][128][8];
  const int tid = threadIdx.x;
  const int lane = tid & 63;
  const int wave = tid >> 6;
  const int l16 = lane & 15, q4 = lane >> 4;
  const int wr = (wave >> 1) * 64, wc = (wave & 1) * 64;
  const size_t row0 = (size_t)blockIdx.x * 128;
  const int col0 = blockIdx.y * 128;

  const int arow = tid >> 1;      // 0..127
  const int ahalf = tid & 1;      // which 16-k half
  const int c0 = ahalf * 2;       // first kchunk written

  f32x4 acc[4][4];
  #pragma unroll
  for (int i = 0; i < 4; ++i)
    #pragma unroll
    for (int j = 0; j < 4; ++j) acc[i][j] = (f32x4)0.f;

  for (int kk = 0; kk < DM; kk += 32) {
    // ---- stage A (fp32 -> hi/lo bf16) and W (pre-split) ----
    const float* ap = A + (row0 + arow) * DM + kk + ahalf * 16;
    float4 f0 = *(const float4*)(ap + 0);
    float4 f1 = *(const float4*)(ap + 4);
    float4 f2 = *(const float4*)(ap + 8);
    float4 f3 = *(const float4*)(ap + 12);
    const short* wph = Wth + (size_t)(col0 + arow) * DM + kk + ahalf * 16;
    const short* wpl = Wtl + (size_t)(col0 + arow) * DM + kk + ahalf * 16;
    short8 wh0 = *(const short8*)(wph);
    short8 wh1 = *(const short8*)(wph + 8);
    short8 wl0 = *(const short8*)(wpl);
    short8 wl1 = *(const short8*)(wpl + 8);

    short8 h0, h1, l0, l1;
    const float* ff = (const float*)&f0;  // f0..f3 contiguous? no — convert explicitly
    {
      float tmp[16];
      *(float4*)&tmp[0] = f0; *(float4*)&tmp[4] = f1;
      *(float4*)&tmp[8] = f2; *(float4*)&tmp[12] = f3;
      #pragma unroll
      for (int e = 0; e < 8; ++e) { short h, l; split_bf16(tmp[e], h, l); h0[e] = h; l0[e] = l; }
      #pragma unroll
      for (int e = 0; e < 8; ++e) { short h, l; split_bf16(tmp[8 + e], h, l); h1[e] = h; l1[e] = l; }
    }
    (void)ff;
    __syncthreads();
    *(short8*)&Ah[c0][arow][0] = h0;
    *(short8*)&Ah[c0 + 1][arow][0] = h1;
    *(short8*)&Al[c0][arow][0] = l0;
    *(short8*)&Al[c0 + 1][arow][0] = l1;
    *(short8*)&Bh[c0][arow][0] = wh0;
    *(short8*)&Bh[c0 + 1][arow][0] = wh1;
    *(short8*)&Bl[c0][arow][0] = wl0;
    *(short8*)&Bl[c0 + 1][arow][0] = wl1;
    __syncthreads();

    // ---- fragments + MFMA ----
    short8 af[4][2], bf_[4][2];
    #pragma unroll
    for (int i = 0; i < 4; ++i) {
      af[i][0] = *(const short8*)&Ah[q4][wr + i * 16 + l16][0];
      af[i][1] = *(const short8*)&Al[q4][wr + i * 16 + l16][0];
    }
    #pragma unroll
    for (int j = 0; j < 4; ++j) {
      bf_[j][0] = *(const short8*)&Bh[q4][wc + j * 16 + l16][0];
      bf_[j][1] = *(const short8*)&Bl[q4][wc + j * 16 + l16][0];
    }
    #pragma unroll
    for (int i = 0; i < 4; ++i)
      #pragma unroll
      for (int j = 0; j < 4; ++j) {
        acc[i][j] = __builtin_amdgcn_mfma_f32_16x16x32_bf16(af[i][0], bf_[j][0], acc[i][j], 0, 0, 0);
        acc[i][j] = __builtin_amdgcn_mfma_f32_16x16x32_bf16(af[i][1], bf_[j][0], acc[i][j], 0, 0, 0);
        acc[i][j] = __builtin_amdgcn_mfma_f32_16x16x32_bf16(af[i][0], bf_[j][1], acc[i][j], 0, 0, 0);
      }
  }

  // ---- epilogue: C/D layout col=lane&15, row=(lane>>4)*4+r ----
  #pragma unroll
  for (int i = 0; i < 4; ++i)
    #pragma unroll
    for (int j = 0; j < 4; ++j) {
      const int col = col0 + wc + j * 16 + l16;
      const float bcol = bias[col];
      #pragma unroll
      for (int r = 0; r < 4; ++r) {
        const size_t row = row0 + wr + i * 16 + q4 * 4 + r;
        V[row * DM + col] = bf16_rne(acc[i][j][r] + bcol);
      }
    }
}

// ---------------------------------------------------------------------------
// Kernel 2: generic fp32 GEMM + bias.  M%32==0, N%32==0, K%32==0.
// 32x32 tile, 256 threads (16x16, 2x2 per thread), BK=32.
// ---------------------------------------------------------------------------
__global__ __launch_bounds__(256) void gemm32(
    const float* __restrict__ A, const float* __restrict__ W,
    const float* __restrict__ bias, float* __restrict__ C,
    int M, int N, int K) {
  __shared__ float As[32][34];   // transposed: As[k][row]
  __shared__ float Bs[32][36];
  const int tid = threadIdx.x;
  const int tx = tid & 15, ty = tid >> 4;
  const int m0 = blockIdx.x * 32, n0 = blockIdx.y * 32;
  const int ar = tid & 31, ak = (tid >> 5) * 4;
  const int bk = tid >> 3, bc = (tid & 7) * 4;
  float acc[2][2] = {{0.f, 0.f}, {0.f, 0.f}};
  for (int kk = 0; kk < K; kk += 32) {
    float4 av = *(const float4*)(A + (size_t)(m0 + ar) * K + kk + ak);
    float4 wv = *(const float4*)(W + (size_t)(kk + bk) * N + n0 + bc);
    __syncthreads();
    As[ak + 0][ar] = av.x; As[ak + 1][ar] = av.y;
    As[ak + 2][ar] = av.z; As[ak + 3][ar] = av.w;
    *(float4*)&Bs[bk][bc] = wv;
    __syncthreads();
    #pragma unroll
    for (int k = 0; k < 32; ++k) {
      const float a0 = As[k][ty * 2], a1 = As[k][ty * 2 + 1];
      const float b0 = Bs[k][tx * 2], b1 = Bs[k][tx * 2 + 1];
      acc[0][0] = fmaf(a0, b0, acc[0][0]);
      acc[0][1] = fmaf(a0, b1, acc[0][1]);
      acc[1][0] = fmaf(a1, b0, acc[1][0]);
      acc[1][1] = fmaf(a1, b1, acc[1][1]);
    }
  }
  const float bi0 = bias[n0 + tx * 2], bi1 = bias[n0 + tx * 2 + 1];
  #pragma unroll
  for (int i = 0; i < 2; ++i) {
    float* cp = C + (size_t)(m0 + ty * 2 + i) * N + n0 + tx * 2;
    cp[0] = acc[i][0] + bi0;
    cp[1] = acc[i][1] + bi1;
  }
}

// ---------------------------------------------------------------------------
// Kernel 3: softmax + bilinear deformable sampling.  One block per (b,q).
// ---------------------------------------------------------------------------
__global__ __launch_bounds__(256) void sample_kernel(
    const float* __restrict__ refp, const unsigned short* __restrict__ v,
    const float* __restrict__ off, const float* __restrict__ logits,
    float* __restrict__ mid) {
  const int bq = blockIdx.x;
  const int b = bq / NQ;
  const int t = threadIdx.x;
  __shared__ float off_sh[192];
  __shared__ float aw_sh[96];
  __shared__ float ref_sh[2];

  if (t < 192) off_sh[t] = off[(size_t)bq * 192 + t];
  else aw_sh[t - 192] = logits[(size_t)bq * 96 + (t - 192)];
  if (t < 32) aw_sh[64 + t] = logits[(size_t)bq * 96 + 64 + t];
  if (t < 2) ref_sh[t] = refp[bq * 4 + t];
  __syncthreads();

  if (t < 8) {
    float m = -1e30f;
    #pragma unroll
    for (int i = 0; i < 12; ++i) m = fmaxf(m, aw_sh[t * 12 + i]);
    float e[12], s = 0.f;
    #pragma unroll
    for (int i = 0; i < 12; ++i) { e[i] = __expf(aw_sh[t * 12 + i] - m); s += e[i]; }
    const float inv = 1.f / s;
    #pragma unroll
    for (int i = 0; i < 12; ++i) aw_sh[t * 12 + i] = e[i] * inv;
  }
  __syncthreads();

  const int h = t >> 5, d = t & 31;
  const float refx = ref_sh[0], refy = ref_sh[1];
  const unsigned short* vb = v + (size_t)b * LV_ * DM + h * 32 + d;
  float acc = 0.f;
  const int LH[3] = {80, 40, 20};
  const int LS[3] = {0, 6400, 8000};
  #pragma unroll
  for (int l = 0; l < 3; ++l) {
    const int hh = LH[l], ww = LH[l], st = LS[l];
    #pragma unroll
    for (int p = 0; p < 4; ++p) {
      const int oi = ((h * 3 + l) * 4 + p) * 2;
      const float aw = aw_sh[h * 12 + l * 4 + p];
      const float sx = fminf(fmaxf(refx + off_sh[oi], 0.f), 1.f);
      const float sy = fminf(fmaxf(refy + off_sh[oi + 1], 0.f), 1.f);
      const float px = sx * (float)ww - 0.5f;
      const float py = sy * (float)hh - 0.5f;
      const float x0f = floorf(px), y0f = floorf(py);
      const float fx = px - x0f, fy = py - y0f;
      const int x0 = (int)x0f, y0 = (int)y0f;
      const int x1 = x0 + 1, y1 = y0 + 1;
      const bool vx0 = (x0 >= 0) & (x0 < ww), vx1 = (x1 >= 0) & (x1 < ww);
      const bool vy0 = (y0 >= 0) & (y0 < hh), vy1 = (y1 >= 0) & (y1 < hh);
      const float w00 = (1.f - fx) * (1.f - fy) * ((vx0 & vy0) ? 1.f : 0.f);
      const float w10 = fx * (1.f - fy) * ((vx1 & vy0) ? 1.f : 0.f);
      const float w01 = (1.f - fx) * fy * ((vx0 & vy1) ? 1.f : 0.f);
      const float w11 = fx * fy * ((vx1 & vy1) ? 1.f : 0.f);
      const int x0c = min(max(x0, 0), ww - 1), x1c = min(max(x1, 0), ww - 1);
      const int y0c = min(max(y0, 0), hh - 1), y1c = min(max(y1, 0), hh - 1);
      const float v00 = __builtin_bit_cast(float, (unsigned int)vb[(size_t)(st + y0c * ww + x0c) * DM] << 16);
      const float v10 = __builtin_bit_cast(float, (unsigned int)vb[(size_t)(st + y0c * ww + x1c) * DM] << 16);
      const float v01 = __builtin_bit_cast(float, (unsigned int)vb[(size_t)(st + y1c * ww + x0c) * DM] << 16);
      const float v11 = __builtin_bit_cast(float, (unsigned int)vb[(size_t)(st + y1c * ww + x1c) * DM] << 16);
      acc += aw * (w00 * v00 + w10 * v10 + w01 * v01 + w11 * v11);
    }
  }
  mid[(size_t)bq * DM + t] = acc;
}

extern "C" void kernel_launch(void* const* d_in, const int* in_sizes, int n_in,
                              void* d_out, int out_size, void* d_ws, size_t ws_size,
                              hipStream_t stream) {
  (void)in_sizes; (void)n_in; (void)out_size; (void)ws_size;
  const float* query = (const float*)d_in[0];
  const float* refp  = (const float*)d_in[1];
  const float* value = (const float*)d_in[2];
  const float* Wv    = (const float*)d_in[3];
  const float* bv    = (const float*)d_in[4];
  const float* Woff  = (const float*)d_in[5];
  const float* boff  = (const float*)d_in[6];
  const float* Wattn = (const float*)d_in[7];
  const float* battn = (const float*)d_in[8];
  const float* Wout  = (const float*)d_in[9];
  const float* bout  = (const float*)d_in[10];
  float* out = (float*)d_out;

  char* ws = (char*)d_ws;
  unsigned short* v_bf = (unsigned short*)ws;            // 68,812,800 B
  short* Wth    = (short*)(ws + 68812800);               // 131,072 B
  short* Wtl    = (short*)(ws + 68943872);               // 131,072 B
  float* offb   = (float*)(ws + 69074944);               // 3,686,400 B
  float* logitb = (float*)(ws + 72761344);               // 1,843,200 B
  float* midb   = (float*)(ws + 74604544);               // 4,915,200 B

  wconv_kernel<<<DM, DM, 0, stream>>>(Wv, Wth, Wtl);
  vproj_mfma<<<dim3((NB * LV_) / 128, 2), 256, 0, stream>>>(value, Wth, Wtl, bv, v_bf);
  gemm32<<<dim3(4800 / 32, 192 / 32), 256, 0, stream>>>(query, Woff, boff, offb, 4800, 192, 256);
  gemm32<<<dim3(4800 / 32, 96 / 32), 256, 0, stream>>>(query, Wattn, battn, logitb, 4800, 96, 256);
  sample_kernel<<<NB * NQ, 256, 0, stream>>>(refp, v_bf, offb, logitb, midb);
  gemm32<<<dim3(4800 / 32, 256 / 32), 256, 0, stream>>>(midb, Wout, bout, out, 4800, 256, 256);
}

// Round 3
// 347.310 us; speedup vs baseline: 1.7945x; 1.0150x over previous
//
#include <hip/hip_runtime.h>
#include <hip/hip_bf16.h>
#include <cstddef>

#define NB 16
#define NQ 300
#define DM 256
#define LV_ 8400

typedef __attribute__((ext_vector_type(8))) short short8;
typedef __attribute__((ext_vector_type(4))) float f32x4;

static __device__ __forceinline__ unsigned short bf16_rne(float f) {
  unsigned int u = __builtin_bit_cast(unsigned int, f);
  u += 0x7FFFu + ((u >> 16) & 1u);
  return (unsigned short)(u >> 16);
}

static __device__ __forceinline__ unsigned int pack_bf2(float a, float b) {
  __hip_bfloat162 p = __float22bfloat162_rn(make_float2(a, b));
  unsigned int u;
  __builtin_memcpy(&u, &p, 4);
  return u;
}

// ---------------------------------------------------------------------------
// Kernel 0: transpose + bf16 round of Wv (256x256).  Wth[n][k].
// ---------------------------------------------------------------------------
__global__ void wconv_kernel(const float* __restrict__ W,
                             unsigned short* __restrict__ Wth) {
  const int n = blockIdx.x, k = threadIdx.x;
  Wth[n * DM + k] = bf16_rne(W[k * DM + n]);
}

// ---------------------------------------------------------------------------
// Kernel 1: v = value @ Wv + bv, bf16 MFMA (A and W rounded to bf16).
// M=134400, N=K=256. 128x128 tile, BK=32, 4 waves 2x2, each 4x4 of 16x16x32.
// Output stored bf16.
// ---------------------------------------------------------------------------
__global__ __launch_bounds__(256) void vproj_mfma(
    const float* __restrict__ A, const unsigned short* __restrict__ Wth,
    const float* __restrict__ bias, unsigned short* __restrict__ V) {
  __shared__ short Ah[4][128][8];   // [k-chunk of 8][row][8 bf16] = 8 KB
  __shared__ short Bh[4][128][8];   // 8 KB
  const int tid = threadIdx.x;
  const int lane = tid & 63;
  const int wave = tid >> 6;
  const int l16 = lane & 15, q4 = lane >> 4;
  const int wr = (wave >> 1) * 64, wc = (wave & 1) * 64;
  const size_t row0 = (size_t)blockIdx.x * 128;
  const int col0 = blockIdx.y * 128;

  const int arow = tid >> 1;     // 0..127
  const int half = tid & 1;      // which 16-k half
  const int c0 = half * 2;

  f32x4 acc[4][4];
  #pragma unroll
  for (int i = 0; i < 4; ++i)
    #pragma unroll
    for (int j = 0; j < 4; ++j) acc[i][j] = (f32x4)0.f;

  const float* ap0 = A + (row0 + arow) * DM + half * 16;
  const unsigned short* wp0 = Wth + (size_t)(col0 + arow) * DM + half * 16;

  for (int kk = 0; kk < DM; kk += 32) {
    const float4 f0 = *(const float4*)(ap0 + kk + 0);
    const float4 f1 = *(const float4*)(ap0 + kk + 4);
    const float4 f2 = *(const float4*)(ap0 + kk + 8);
    const float4 f3 = *(const float4*)(ap0 + kk + 12);
    const uint4 w0 = *(const uint4*)(wp0 + kk);
    const uint4 w1 = *(const uint4*)(wp0 + kk + 8);
    uint4 p0, p1;
    p0.x = pack_bf2(f0.x, f0.y); p0.y = pack_bf2(f0.z, f0.w);
    p0.z = pack_bf2(f1.x, f1.y); p0.w = pack_bf2(f1.z, f1.w);
    p1.x = pack_bf2(f2.x, f2.y); p1.y = pack_bf2(f2.z, f2.w);
    p1.z = pack_bf2(f3.x, f3.y); p1.w = pack_bf2(f3.z, f3.w);
    __syncthreads();
    *(uint4*)&Ah[c0][arow][0]     = p0;
    *(uint4*)&Ah[c0 + 1][arow][0] = p1;
    *(uint4*)&Bh[c0][arow][0]     = w0;
    *(uint4*)&Bh[c0 + 1][arow][0] = w1;
    __syncthreads();

    short8 af[4], bfr[4];
    #pragma unroll
    for (int i = 0; i < 4; ++i)
      af[i] = *(const short8*)&Ah[q4][wr + i * 16 + l16][0];
    #pragma unroll
    for (int j = 0; j < 4; ++j)
      bfr[j] = *(const short8*)&Bh[q4][wc + j * 16 + l16][0];
    #pragma unroll
    for (int i = 0; i < 4; ++i)
      #pragma unroll
      for (int j = 0; j < 4; ++j)
        acc[i][j] = __builtin_amdgcn_mfma_f32_16x16x32_bf16(af[i], bfr[j], acc[i][j], 0, 0, 0);
  }

  // C/D layout: col = lane&15, row = (lane>>4)*4 + r
  #pragma unroll
  for (int i = 0; i < 4; ++i)
    #pragma unroll
    for (int j = 0; j < 4; ++j) {
      const int col = col0 + wc + j * 16 + l16;
      const float bcol = bias[col];
      #pragma unroll
      for (int r = 0; r < 4; ++r) {
        const size_t row = row0 + wr + i * 16 + q4 * 4 + r;
        V[row * DM + col] = bf16_rne(acc[i][j][r] + bcol);
      }
    }
}

// ---------------------------------------------------------------------------
// Kernel 2: fp32 GEMM + bias, 64x64 tile, BK=16, 256 threads, 4x4 microtile.
// Requires M%64==0, K%16==0, N%4==0 (column-guarded for N not multiple of 64).
// ---------------------------------------------------------------------------
__global__ __launch_bounds__(256) void gemm64(
    const float* __restrict__ A, const float* __restrict__ W,
    const float* __restrict__ bias, float* __restrict__ C,
    int M, int N, int K) {
  __shared__ float As[16][64];   // As[k][m]
  __shared__ float Bs[16][64];   // Bs[k][n]
  const int tid = threadIdx.x;
  const int tx = tid & 15, ty = tid >> 4;
  const int m0 = blockIdx.x * 64, n0 = blockIdx.y * 64;
  const int ar = tid & 63, ak4 = (tid >> 6) * 4;
  const int bk = tid >> 4, bc4 = (tid & 15) * 4;
  const int bcol = n0 + bc4;

  float acc[4][4];
  #pragma unroll
  for (int i = 0; i < 4; ++i)
    #pragma unroll
    for (int j = 0; j < 4; ++j) acc[i][j] = 0.f;

  for (int kk = 0; kk < K; kk += 16) {
    const float4 av = *(const float4*)(A + (size_t)(m0 + ar) * K + kk + ak4);
    float4 wv = make_float4(0.f, 0.f, 0.f, 0.f);
    if (bcol < N) wv = *(const float4*)(W + (size_t)(kk + bk) * N + bcol);
    __syncthreads();
    As[ak4 + 0][ar] = av.x;
    As[ak4 + 1][ar] = av.y;
    As[ak4 + 2][ar] = av.z;
    As[ak4 + 3][ar] = av.w;
    *(float4*)&Bs[bk][bc4] = wv;
    __syncthreads();
    #pragma unroll
    for (int k = 0; k < 16; ++k) {
      const float4 a4 = *(const float4*)&As[k][ty * 4];
      const float4 b4 = *(const float4*)&Bs[k][tx * 4];
      const float* aa = (const float*)&a4;
      const float* bb = (const float*)&b4;
      #pragma unroll
      for (int i = 0; i < 4; ++i)
        #pragma unroll
        for (int j = 0; j < 4; ++j)
          acc[i][j] = fmaf(aa[i], bb[j], acc[i][j]);
    }
  }

  if (n0 + tx * 4 < N) {
    const float4 bi = *(const float4*)&bias[n0 + tx * 4];
    const float* bb = (const float*)&bi;
    #pragma unroll
    for (int i = 0; i < 4; ++i) {
      float4 o;
      o.x = acc[i][0] + bb[0];
      o.y = acc[i][1] + bb[1];
      o.z = acc[i][2] + bb[2];
      o.w = acc[i][3] + bb[3];
      *(float4*)(C + (size_t)(m0 + ty * 4 + i) * N + n0 + tx * 4) = o;
    }
  }
}

// ---------------------------------------------------------------------------
// Kernel 3: softmax + bilinear deformable sampling. 2 queries per block.
// Phase 1: 16 threads softmax; Phase 2: 192 threads build corner descriptors
// (absolute index + combined weight, computed ONCE per (q,h,l,p));
// Phase 3: 256 threads gather (2 dims per thread, packed 4B loads).
// ---------------------------------------------------------------------------
__global__ __launch_bounds__(256) void sample_kernel(
    const float* __restrict__ refp, const unsigned short* __restrict__ v,
    const float* __restrict__ off, const float* __restrict__ logits,
    float* __restrict__ mid) {
  const int bq0 = blockIdx.x * 2;
  const int b = bq0 / NQ;
  const int t = threadIdx.x;
  __shared__ float off_sh[2][192];
  __shared__ float aw_sh[2][96];
  __shared__ int   idx_sh[2][96][4];
  __shared__ float wt_sh[2][96][4];
  __shared__ float ref_sh[2][2];

  {
    const float* osrc = off + (size_t)bq0 * 192;
    float* odst = &off_sh[0][0];
    odst[t] = osrc[t];
    if (t < 128) odst[256 + t] = osrc[256 + t];
    const float* lsrc = logits + (size_t)bq0 * 96;
    if (t < 192) (&aw_sh[0][0])[t] = lsrc[t];
    if (t < 4) ref_sh[t >> 1][t & 1] = refp[(bq0 + (t >> 1)) * 4 + (t & 1)];
  }
  __syncthreads();

  if (t < 16) {
    const int q = t >> 3, h = t & 7;
    float* aw = &aw_sh[q][h * 12];
    float m = -1e30f;
    #pragma unroll
    for (int i = 0; i < 12; ++i) m = fmaxf(m, aw[i]);
    float e[12], s = 0.f;
    #pragma unroll
    for (int i = 0; i < 12; ++i) { e[i] = __expf(aw[i] - m); s += e[i]; }
    const float inv = 1.f / s;
    #pragma unroll
    for (int i = 0; i < 12; ++i) aw[i] = e[i] * inv;
  }
  __syncthreads();

  if (t < 192) {
    const int q = t / 96, r = t - q * 96;
    const int h = r / 12, lp = r - h * 12;
    const int l = lp >> 2, p = lp & 3;
    const int LH[3] = {80, 40, 20};
    const int LS[3] = {0, 6400, 8000};
    const int hh = LH[l], ww = LH[l], st = LS[l];
    const int oi = ((h * 3 + l) * 4 + p) * 2;
    const float aw = aw_sh[q][h * 12 + lp];
    const float sx = fminf(fmaxf(ref_sh[q][0] + off_sh[q][oi], 0.f), 1.f);
    const float sy = fminf(fmaxf(ref_sh[q][1] + off_sh[q][oi + 1], 0.f), 1.f);
    const float px = sx * (float)ww - 0.5f;
    const float py = sy * (float)hh - 0.5f;
    const float x0f = floorf(px), y0f = floorf(py);
    const float fx = px - x0f, fy = py - y0f;
    const int x0 = (int)x0f, y0 = (int)y0f;
    const int x1 = x0 + 1, y1 = y0 + 1;
    const bool vx0 = (x0 >= 0) & (x0 < ww), vx1 = (x1 >= 0) & (x1 < ww);
    const bool vy0 = (y0 >= 0) & (y0 < hh), vy1 = (y1 >= 0) & (y1 < hh);
    const int x0c = min(max(x0, 0), ww - 1), x1c = min(max(x1, 0), ww - 1);
    const int y0c = min(max(y0, 0), hh - 1), y1c = min(max(y1, 0), hh - 1);
    idx_sh[q][r][0] = st + y0c * ww + x0c;
    idx_sh[q][r][1] = st + y0c * ww + x1c;
    idx_sh[q][r][2] = st + y1c * ww + x0c;
    idx_sh[q][r][3] = st + y1c * ww + x1c;
    wt_sh[q][r][0] = aw * (1.f - fx) * (1.f - fy) * ((vx0 & vy0) ? 1.f : 0.f);
    wt_sh[q][r][1] = aw * fx * (1.f - fy) * ((vx1 & vy0) ? 1.f : 0.f);
    wt_sh[q][r][2] = aw * (1.f - fx) * fy * ((vx0 & vy1) ? 1.f : 0.f);
    wt_sh[q][r][3] = aw * fx * fy * ((vx1 & vy1) ? 1.f : 0.f);
  }
  __syncthreads();

  // gather: q = t>>7, head = (t>>4)&7, dim-pair = t&15
  const int q = t >> 7, h = (t >> 4) & 7, dp = t & 15;
  const unsigned short* vb = v + (size_t)b * LV_ * DM + h * 32 + dp * 2;
  float ax = 0.f, ay = 0.f;
  #pragma unroll
  for (int r = 0; r < 12; ++r) {
    const int rr = h * 12 + r;
    #pragma unroll
    for (int c = 0; c < 4; ++c) {
      const int id = idx_sh[q][rr][c];
      const float w = wt_sh[q][rr][c];
      const unsigned int u = *(const unsigned int*)(vb + (size_t)id * DM);
      ax = fmaf(w, __builtin_bit_cast(float, u << 16), ax);
      ay = fmaf(w, __builtin_bit_cast(float, u & 0xFFFF0000u), ay);
    }
  }
  float2 o; o.x = ax; o.y = ay;
  *(float2*)(mid + (size_t)(bq0 + q) * DM + h * 32 + dp * 2) = o;
}

extern "C" void kernel_launch(void* const* d_in, const int* in_sizes, int n_in,
                              void* d_out, int out_size, void* d_ws, size_t ws_size,
                              hipStream_t stream) {
  (void)in_sizes; (void)n_in; (void)out_size; (void)ws_size;
  const float* query = (const float*)d_in[0];
  const float* refp  = (const float*)d_in[1];
  const float* value = (const float*)d_in[2];
  const float* Wv    = (const float*)d_in[3];
  const float* bv    = (const float*)d_in[4];
  const float* Woff  = (const float*)d_in[5];
  const float* boff  = (const float*)d_in[6];
  const float* Wattn = (const float*)d_in[7];
  const float* battn = (const float*)d_in[8];
  const float* Wout  = (const float*)d_in[9];
  const float* bout  = (const float*)d_in[10];
  float* out = (float*)d_out;

  char* ws = (char*)d_ws;
  unsigned short* v_bf = (unsigned short*)ws;              // 68,812,800 B
  unsigned short* Wth  = (unsigned short*)(ws + 68812800); // 131,072 B
  float* offb   = (float*)(ws + 68943872);                 // 3,686,400 B
  float* logitb = (float*)(ws + 72630272);                 // 1,843,200 B
  float* midb   = (float*)(ws + 74473472);                 // 4,915,200 B

  wconv_kernel<<<DM, DM, 0, stream>>>(Wv, Wth);
  vproj_mfma<<<dim3((NB * LV_) / 128, 2), 256, 0, stream>>>(value, Wth, bv, v_bf);
  gemm64<<<dim3(75, 3), 256, 0, stream>>>(query, Woff, boff, offb, 4800, 192, 256);
  gemm64<<<dim3(75, 2), 256, 0, stream>>>(query, Wattn, battn, logitb, 4800, 96, 256);
  sample_kernel<<<2400, 256, 0, stream>>>(refp, v_bf, offb, logitb, midb);
  gemm64<<<dim3(75, 4), 256, 0, stream>>>(midb, Wout, bout, out, 4800, 256, 256);
}

// Round 4
// 295.585 us; speedup vs baseline: 2.1085x; 1.1750x over previous
//
#include <hip/hip_runtime.h>
#include <hip/hip_bf16.h>
#include <cstddef>

#define NB 16
#define NQ 300
#define DM 256
#define LV_ 8400

typedef __attribute__((ext_vector_type(8))) short short8;
typedef __attribute__((ext_vector_type(4))) float f32x4;

static __device__ __forceinline__ unsigned short bf16_rne(float f) {
  unsigned int u = __builtin_bit_cast(unsigned int, f);
  u += 0x7FFFu + ((u >> 16) & 1u);
  return (unsigned short)(u >> 16);
}

static __device__ __forceinline__ unsigned int pack_bf2(float a, float b) {
  __hip_bfloat162 p = __float22bfloat162_rn(make_float2(a, b));
  unsigned int u;
  __builtin_memcpy(&u, &p, 4);
  return u;
}

// ---------------------------------------------------------------------------
// Kernel 0: coalesced transpose + bf16 round of Wv and Wout.
// dst[n][k] = bf16(src[k][n]).  grid (8,8,2), 256 threads.
// ---------------------------------------------------------------------------
__global__ __launch_bounds__(256) void prep_kernel(
    const float* __restrict__ Wv, const float* __restrict__ Wout,
    unsigned short* __restrict__ Wth, unsigned short* __restrict__ WoutT) {
  const float* src = blockIdx.z ? Wout : Wv;
  unsigned short* dst = blockIdx.z ? WoutT : Wth;
  __shared__ float tle[32][33];
  const int k0 = blockIdx.x * 32, n0 = blockIdx.y * 32;
  const int xx = threadIdx.x & 31, y4 = (threadIdx.x >> 5) * 4;
  #pragma unroll
  for (int i = 0; i < 4; ++i)
    tle[y4 + i][xx] = src[(size_t)(k0 + y4 + i) * DM + n0 + xx];
  __syncthreads();
  #pragma unroll
  for (int i = 0; i < 4; ++i)
    dst[(size_t)(n0 + y4 + i) * DM + k0 + xx] = bf16_rne(tle[xx][y4 + i]);
}

// ---------------------------------------------------------------------------
// Kernel 1: v = value @ Wv + bv, bf16 MFMA, register-prefetch pipelined.
// M=134400, N=K=256. 128x128 tile, BK=32, 4 waves 2x2, each 4x4 of 16x16x32.
// Output stored bf16.
// ---------------------------------------------------------------------------
__global__ __launch_bounds__(256) void vproj_mfma(
    const float* __restrict__ A, const unsigned short* __restrict__ Wth,
    const float* __restrict__ bias, unsigned short* __restrict__ V) {
  __shared__ short Ah[4][128][8];   // [k-chunk of 8][row][8 bf16] = 8 KB
  __shared__ short Bh[4][128][8];   // 8 KB
  const int tid = threadIdx.x;
  const int lane = tid & 63;
  const int wave = tid >> 6;
  const int l16 = lane & 15, q4 = lane >> 4;
  const int wr = (wave >> 1) * 64, wc = (wave & 1) * 64;
  const size_t row0 = (size_t)blockIdx.x * 128;
  const int col0 = blockIdx.y * 128;

  const int arow = tid >> 1;     // 0..127
  const int half = tid & 1;      // which 16-k half
  const int c0 = half * 2;

  f32x4 acc[4][4];
  #pragma unroll
  for (int i = 0; i < 4; ++i)
    #pragma unroll
    for (int j = 0; j < 4; ++j) acc[i][j] = (f32x4)0.f;

  const float* ap0 = A + (row0 + arow) * DM + half * 16;
  const unsigned short* wp0 = Wth + (size_t)(col0 + arow) * DM + half * 16;

  // preload tile 0
  float4 f0 = *(const float4*)(ap0 + 0);
  float4 f1 = *(const float4*)(ap0 + 4);
  float4 f2 = *(const float4*)(ap0 + 8);
  float4 f3 = *(const float4*)(ap0 + 12);
  uint4 w0 = *(const uint4*)(wp0);
  uint4 w1 = *(const uint4*)(wp0 + 8);

  for (int kk = 0; kk < DM; kk += 32) {
    uint4 p0, p1;
    p0.x = pack_bf2(f0.x, f0.y); p0.y = pack_bf2(f0.z, f0.w);
    p0.z = pack_bf2(f1.x, f1.y); p0.w = pack_bf2(f1.z, f1.w);
    p1.x = pack_bf2(f2.x, f2.y); p1.y = pack_bf2(f2.z, f2.w);
    p1.z = pack_bf2(f3.x, f3.y); p1.w = pack_bf2(f3.z, f3.w);
    uint4 cw0 = w0, cw1 = w1;
    __syncthreads();
    *(uint4*)&Ah[c0][arow][0]     = p0;
    *(uint4*)&Ah[c0 + 1][arow][0] = p1;
    *(uint4*)&Bh[c0][arow][0]     = cw0;
    *(uint4*)&Bh[c0 + 1][arow][0] = cw1;
    __syncthreads();

    // prefetch next tile (overlaps fragment reads + MFMA below)
    if (kk + 32 < DM) {
      f0 = *(const float4*)(ap0 + kk + 32);
      f1 = *(const float4*)(ap0 + kk + 36);
      f2 = *(const float4*)(ap0 + kk + 40);
      f3 = *(const float4*)(ap0 + kk + 44);
      w0 = *(const uint4*)(wp0 + kk + 32);
      w1 = *(const uint4*)(wp0 + kk + 40);
    }

    short8 af[4], bfr[4];
    #pragma unroll
    for (int i = 0; i < 4; ++i)
      af[i] = *(const short8*)&Ah[q4][wr + i * 16 + l16][0];
    #pragma unroll
    for (int j = 0; j < 4; ++j)
      bfr[j] = *(const short8*)&Bh[q4][wc + j * 16 + l16][0];
    #pragma unroll
    for (int i = 0; i < 4; ++i)
      #pragma unroll
      for (int j = 0; j < 4; ++j)
        acc[i][j] = __builtin_amdgcn_mfma_f32_16x16x32_bf16(af[i], bfr[j], acc[i][j], 0, 0, 0);
  }

  // C/D layout: col = lane&15, row = (lane>>4)*4 + r
  #pragma unroll
  for (int i = 0; i < 4; ++i)
    #pragma unroll
    for (int j = 0; j < 4; ++j) {
      const int col = col0 + wc + j * 16 + l16;
      const float bcol = bias[col];
      #pragma unroll
      for (int r = 0; r < 4; ++r) {
        const size_t row = row0 + wr + i * 16 + q4 * 4 + r;
        V[row * DM + col] = bf16_rne(acc[i][j][r] + bcol);
      }
    }
}

// ---------------------------------------------------------------------------
// Kernel 2: fused query projections (offsets N=192 + logits N=96), fp32.
// 32x32 tile, BK=32, 256 threads, 2x2 microtile, register-prefetched.
// grid (150, 9): by<6 -> Woff tile, else -> Wattn tile.
// ---------------------------------------------------------------------------
__global__ __launch_bounds__(256) void gemm_qp(
    const float* __restrict__ q,
    const float* __restrict__ Woff, const float* __restrict__ boff,
    const float* __restrict__ Wattn, const float* __restrict__ battn,
    float* __restrict__ offb, float* __restrict__ logitb) {
  const int by = blockIdx.y;
  const float* W; const float* bias; float* C; int N, c0;
  if (by < 6) { W = Woff;  bias = boff;  C = offb;   N = 192; c0 = by * 32; }
  else        { W = Wattn; bias = battn; C = logitb; N = 96;  c0 = (by - 6) * 32; }
  const int m0 = blockIdx.x * 32;

  __shared__ float As[32][33];   // As[k][m]
  __shared__ float Bs[32][33];   // Bs[k][n]
  const int tid = threadIdx.x;
  const int ar = tid >> 3, ak = (tid & 7) * 4;
  const int kr = tid >> 3, bc = (tid & 7) * 4;
  const int tx = tid & 15, ty = tid >> 4;

  const float* apt = q + (size_t)(m0 + ar) * DM + ak;
  float4 av = *(const float4*)apt;
  float4 wv = *(const float4*)(W + (size_t)kr * N + c0 + bc);

  float acc[2][2] = {{0.f, 0.f}, {0.f, 0.f}};
  for (int kk = 0; kk < DM; kk += 32) {
    __syncthreads();
    As[ak + 0][ar] = av.x;
    As[ak + 1][ar] = av.y;
    As[ak + 2][ar] = av.z;
    As[ak + 3][ar] = av.w;
    *(float4*)&Bs[kr][bc] = wv;
    __syncthreads();
    if (kk + 32 < DM) {
      av = *(const float4*)(apt + kk + 32);
      wv = *(const float4*)(W + (size_t)(kk + 32 + kr) * N + c0 + bc);
    }
    #pragma unroll
    for (int k = 0; k < 32; ++k) {
      const float2 a2 = *(const float2*)&As[k][ty * 2];
      const float2 b2 = *(const float2*)&Bs[k][tx * 2];
      acc[0][0] = fmaf(a2.x, b2.x, acc[0][0]);
      acc[0][1] = fmaf(a2.x, b2.y, acc[0][1]);
      acc[1][0] = fmaf(a2.y, b2.x, acc[1][0]);
      acc[1][1] = fmaf(a2.y, b2.y, acc[1][1]);
    }
  }
  const float b0 = bias[c0 + tx * 2], b1 = bias[c0 + tx * 2 + 1];
  #pragma unroll
  for (int i = 0; i < 2; ++i) {
    float2 o; o.x = acc[i][0] + b0; o.y = acc[i][1] + b1;
    *(float2*)&C[(size_t)(m0 + ty * 2 + i) * N + c0 + tx * 2] = o;
  }
}

// ---------------------------------------------------------------------------
// Kernel 3: softmax + bilinear deformable sampling. 2 queries per block,
// XCD-locality swizzle (each XCD serves 2 batches -> 8.6 MB L2 working set).
// Writes mid as bf16.
// ---------------------------------------------------------------------------
__global__ __launch_bounds__(256) void sample_kernel(
    const float* __restrict__ refp, const unsigned short* __restrict__ v,
    const float* __restrict__ off, const float* __restrict__ logits,
    unsigned short* __restrict__ mid) {
  // swizzle: XCD = blockIdx%8 (round-robin); give each XCD batches {c, c+8}
  const int x = blockIdx.x;
  const int c8 = x & 7, kb = x >> 3;          // kb in [0,300)
  const int b = c8 + (kb >= 150 ? 8 : 0);
  const int qp = (kb >= 150 ? kb - 150 : kb);
  const int bq0 = b * NQ + qp * 2;
  const int t = threadIdx.x;
  __shared__ float off_sh[2][192];
  __shared__ float aw_sh[2][96];
  __shared__ int   idx_sh[2][96][4];
  __shared__ float wt_sh[2][96][4];
  __shared__ float ref_sh[2][2];

  {
    const float* osrc = off + (size_t)bq0 * 192;
    float* odst = &off_sh[0][0];
    odst[t] = osrc[t];
    if (t < 128) odst[256 + t] = osrc[256 + t];
    const float* lsrc = logits + (size_t)bq0 * 96;
    if (t < 192) (&aw_sh[0][0])[t] = lsrc[t];
    if (t < 4) ref_sh[t >> 1][t & 1] = refp[(bq0 + (t >> 1)) * 4 + (t & 1)];
  }
  __syncthreads();

  if (t < 16) {
    const int q = t >> 3, h = t & 7;
    float* aw = &aw_sh[q][h * 12];
    float m = -1e30f;
    #pragma unroll
    for (int i = 0; i < 12; ++i) m = fmaxf(m, aw[i]);
    float e[12], s = 0.f;
    #pragma unroll
    for (int i = 0; i < 12; ++i) { e[i] = __expf(aw[i] - m); s += e[i]; }
    const float inv = 1.f / s;
    #pragma unroll
    for (int i = 0; i < 12; ++i) aw[i] = e[i] * inv;
  }
  __syncthreads();

  if (t < 192) {
    const int q = t / 96, r = t - q * 96;
    const int h = r / 12, lp = r - h * 12;
    const int l = lp >> 2, p = lp & 3;
    const int LH[3] = {80, 40, 20};
    const int LS[3] = {0, 6400, 8000};
    const int hh = LH[l], ww = LH[l], st = LS[l];
    const int oi = ((h * 3 + l) * 4 + p) * 2;
    const float aw = aw_sh[q][h * 12 + lp];
    const float sx = fminf(fmaxf(ref_sh[q][0] + off_sh[q][oi], 0.f), 1.f);
    const float sy = fminf(fmaxf(ref_sh[q][1] + off_sh[q][oi + 1], 0.f), 1.f);
    const float px = sx * (float)ww - 0.5f;
    const float py = sy * (float)hh - 0.5f;
    const float x0f = floorf(px), y0f = floorf(py);
    const float fx = px - x0f, fy = py - y0f;
    const int x0 = (int)x0f, y0 = (int)y0f;
    const int x1 = x0 + 1, y1 = y0 + 1;
    const bool vx0 = (x0 >= 0) & (x0 < ww), vx1 = (x1 >= 0) & (x1 < ww);
    const bool vy0 = (y0 >= 0) & (y0 < hh), vy1 = (y1 >= 0) & (y1 < hh);
    const int x0c = min(max(x0, 0), ww - 1), x1c = min(max(x1, 0), ww - 1);
    const int y0c = min(max(y0, 0), hh - 1), y1c = min(max(y1, 0), hh - 1);
    idx_sh[q][r][0] = st + y0c * ww + x0c;
    idx_sh[q][r][1] = st + y0c * ww + x1c;
    idx_sh[q][r][2] = st + y1c * ww + x0c;
    idx_sh[q][r][3] = st + y1c * ww + x1c;
    wt_sh[q][r][0] = aw * (1.f - fx) * (1.f - fy) * ((vx0 & vy0) ? 1.f : 0.f);
    wt_sh[q][r][1] = aw * fx * (1.f - fy) * ((vx1 & vy0) ? 1.f : 0.f);
    wt_sh[q][r][2] = aw * (1.f - fx) * fy * ((vx0 & vy1) ? 1.f : 0.f);
    wt_sh[q][r][3] = aw * fx * fy * ((vx1 & vy1) ? 1.f : 0.f);
  }
  __syncthreads();

  // gather: q = t>>7, head = (t>>4)&7, dim-pair = t&15
  const int q = t >> 7, h = (t >> 4) & 7, dp = t & 15;
  const unsigned short* vb = v + (size_t)b * LV_ * DM + h * 32 + dp * 2;
  float ax = 0.f, ay = 0.f;
  #pragma unroll
  for (int r = 0; r < 12; ++r) {
    const int rr = h * 12 + r;
    #pragma unroll
    for (int cc = 0; cc < 4; ++cc) {
      const int id = idx_sh[q][rr][cc];
      const float w = wt_sh[q][rr][cc];
      const unsigned int u = *(const unsigned int*)(vb + (size_t)id * DM);
      ax = fmaf(w, __builtin_bit_cast(float, u << 16), ax);
      ay = fmaf(w, __builtin_bit_cast(float, u & 0xFFFF0000u), ay);
    }
  }
  unsigned short* mp = mid + (size_t)(bq0 + q) * DM + h * 32 + dp * 2;
  *(unsigned int*)mp = pack_bf2(ax, ay);
}

// ---------------------------------------------------------------------------
// Kernel 4: out = mid @ Wout + bout, bf16 MFMA, 64x64 tile, BK=32,
// register-prefetch pipelined.  grid (75, 4).
// ---------------------------------------------------------------------------
__global__ __launch_bounds__(256) void outp_mfma(
    const unsigned short* __restrict__ midb, const unsigned short* __restrict__ WoutT,
    const float* __restrict__ bias, float* __restrict__ out) {
  __shared__ short Ah[4][64][8];   // 4 KB
  __shared__ short Bh[4][64][8];   // 4 KB
  const int tid = threadIdx.x;
  const int lane = tid & 63;
  const int wave = tid >> 6;
  const int l16 = lane & 15, q4 = lane >> 4;
  const int wc = wave * 16;
  const int m0 = blockIdx.x * 64, col0 = blockIdx.y * 64;

  const int r = tid >> 2, ch = tid & 3;   // staging: row, k-chunk
  const unsigned short* apt = midb + (size_t)(m0 + r) * DM + ch * 8;
  const unsigned short* wpt = WoutT + (size_t)(col0 + r) * DM + ch * 8;
  uint4 am = *(const uint4*)apt;
  uint4 wm = *(const uint4*)wpt;

  f32x4 acc[4];
  #pragma unroll
  for (int i = 0; i < 4; ++i) acc[i] = (f32x4)0.f;

  for (int kk = 0; kk < DM; kk += 32) {
    __syncthreads();
    *(uint4*)&Ah[ch][r][0] = am;
    *(uint4*)&Bh[ch][r][0] = wm;
    __syncthreads();
    if (kk + 32 < DM) {
      am = *(const uint4*)(apt + kk + 32);
      wm = *(const uint4*)(wpt + kk + 32);
    }
    const short8 bfrag = *(const short8*)&Bh[q4][wc + l16][0];
    #pragma unroll
    for (int i = 0; i < 4; ++i) {
      const short8 af = *(const short8*)&Ah[q4][i * 16 + l16][0];
      acc[i] = __builtin_amdgcn_mfma_f32_16x16x32_bf16(af, bfrag, acc[i], 0, 0, 0);
    }
  }

  const int col = col0 + wc + l16;
  const float bcol = bias[col];
  #pragma unroll
  for (int i = 0; i < 4; ++i)
    #pragma unroll
    for (int rr = 0; rr < 4; ++rr)
      out[(size_t)(m0 + i * 16 + q4 * 4 + rr) * DM + col] = acc[i][rr] + bcol;
}

extern "C" void kernel_launch(void* const* d_in, const int* in_sizes, int n_in,
                              void* d_out, int out_size, void* d_ws, size_t ws_size,
                              hipStream_t stream) {
  (void)in_sizes; (void)n_in; (void)out_size; (void)ws_size;
  const float* query = (const float*)d_in[0];
  const float* refp  = (const float*)d_in[1];
  const float* value = (const float*)d_in[2];
  const float* Wv    = (const float*)d_in[3];
  const float* bv    = (const float*)d_in[4];
  const float* Woff  = (const float*)d_in[5];
  const float* boff  = (const float*)d_in[6];
  const float* Wattn = (const float*)d_in[7];
  const float* battn = (const float*)d_in[8];
  const float* Wout  = (const float*)d_in[9];
  const float* bout  = (const float*)d_in[10];
  float* out = (float*)d_out;

  char* ws = (char*)d_ws;
  unsigned short* v_bf  = (unsigned short*)ws;              // 68,812,800 B
  unsigned short* Wth   = (unsigned short*)(ws + 68812800); // 131,072 B
  unsigned short* WoutT = (unsigned short*)(ws + 68943872); // 131,072 B
  float* offb   = (float*)(ws + 69074944);                  // 3,686,400 B
  float* logitb = (float*)(ws + 72761344);                  // 1,843,200 B
  unsigned short* midb = (unsigned short*)(ws + 74604544);  // 2,457,600 B

  prep_kernel<<<dim3(8, 8, 2), 256, 0, stream>>>(Wv, Wout, Wth, WoutT);
  gemm_qp<<<dim3(150, 9), 256, 0, stream>>>(query, Woff, boff, Wattn, battn, offb, logitb);
  vproj_mfma<<<dim3((NB * LV_) / 128, 2), 256, 0, stream>>>(value, Wth, bv, v_bf);
  sample_kernel<<<2400, 256, 0, stream>>>(refp, v_bf, offb, logitb, midb);
  outp_mfma<<<dim3(75, 4), 256, 0, stream>>>(midb, WoutT, bout, out);
}